// Round 5
// baseline (114.128 us; speedup 1.0000x reference)
//
#include <hip/hip_runtime.h>

#define BB 8
#define TT 512
#define DD 64
#define S_SCALE 1.2011224087864498f   // sqrt(log2(e)); exp(-u^2) = exp2(-(S*u)^2)

__device__ __forceinline__ float fast_exp2(float v) {
#if __has_builtin(__builtin_amdgcn_exp2f)
    return __builtin_amdgcn_exp2f(v);
#else
    return exp2f(v);
#endif
}
__device__ __forceinline__ float fast_rcp(float v) {
#if __has_builtin(__builtin_amdgcn_rcpf)
    return __builtin_amdgcn_rcpf(v);
#else
    return 1.0f / v;
#endif
}

// ---------------- kernel 1: v = x@W^T + b ; xsc = S*x ----------------
__global__ __launch_bounds__(256) void rbf_pre(
    const float* __restrict__ x, const float* __restrict__ W,
    const float* __restrict__ bias, float* __restrict__ xsc,
    float* __restrict__ vv)
{
    const int t = threadIdx.x;
    const int w = t >> 6, l = t & 63;
    const int row = blockIdx.x * 4 + w;
    const float* xr = x + (size_t)row * DD;
    const float* wr = W + (size_t)l * DD;
    float acc = bias[l];
    #pragma unroll
    for (int d = 0; d < DD; d += 4) {
        float4 xv = *(const float4*)(xr + d);
        float4 wv = *(const float4*)(wr + d);
        acc = fmaf(xv.x, wv.x, acc); acc = fmaf(xv.y, wv.y, acc);
        acc = fmaf(xv.z, wv.z, acc); acc = fmaf(xv.w, wv.w, acc);
    }
    vv [(size_t)row * DD + l] = acc;
    xsc[(size_t)row * DD + l] = xr[l] * S_SCALE;
}

// ---------------- kernel 2: symmetric pairwise tiles ----------------
// Block: (b, strip st of 16 i, tile jt of 64 j), launched for st <= 4*jt+3.
//   A-blocks (st < 4*jt): compute once, write rows out[i,j] AND cols out[j,i].
//   D-blocks (st in [4jt,4jt+3]): full row compute only.
// Lane = j. xj: 64 VGPRs (one-time LDS transpose). vj: LDS per i-iter.
// xi/vi: wave-uniform loads (scalar/L1 path). No cross-lane reductions.
__global__ __launch_bounds__(256, 3) void rbf_pair(
    const float* __restrict__ xsc, const float* __restrict__ vv,
    float* __restrict__ out)
{
    const int bid = blockIdx.x;
    const int b   = bid / 144;
    const int idx = bid - b * 144;
    int st, jt, isA;
    if (idx < 32) { jt = idx >> 2; st = 4 * jt + (idx & 3); isA = 0; }
    else {
        int k = idx - 32, tt = 1;
        while (k >= 4 * tt) { k -= 4 * tt; ++tt; }
        jt = tt; st = k; isA = 1;
    }
    const int tid = threadIdx.x;
    const int w = __builtin_amdgcn_readfirstlane(tid >> 6);
    const int l = tid & 63;

    __shared__ float xls[64 * 68];    // j-tile of xsc, row stride 68 (17 granules)
    __shared__ float vls[64 * 68];    // j-tile of v
    __shared__ float cbuf[64 * 20];   // col outputs [j][iloc], stride 20

    // ---- stage j-tile (coalesced) ----
    const size_t jbase = ((size_t)b * TT + (size_t)jt * 64) * DD;
    #pragma unroll
    for (int u = 0; u < 4; ++u) {
        int gg = u * 256 + tid;               // f4 granule: row = gg>>4, col = gg&15
        int r = gg >> 4, c = gg & 15;
        float4 a  = *(const float4*)(xsc + jbase + (size_t)r * DD + c * 4);
        float4 vq = *(const float4*)(vv  + jbase + (size_t)r * DD + c * 4);
        *(float4*)(&xls[r * 68 + c * 4]) = a;
        *(float4*)(&vls[r * 68 + c * 4]) = vq;
    }
    __syncthreads();

    // lane-resident xj row (64 VGPRs)
    float4 xj_r[16];
    #pragma unroll
    for (int c = 0; c < 16; ++c)
        xj_r[c] = *(const float4*)(&xls[l * 68 + c * 4]);

    const int i0 = st * 16;
    float* outb = out + (size_t)b * TT * TT;

    #pragma unroll 1
    for (int r = 0; r < 4; ++r) {
        const int iloc = w * 4 + r;
        const int irow = i0 + iloc;                                // wave-uniform
        const float4* xi4 = (const float4*)(xsc + ((size_t)b * TT + irow) * DD);
        const float4* vi4 = (const float4*)(vv  + ((size_t)b * TT + irow) * DD);
        float nr0 = 0.f, nr1 = 0.f, nc0 = 0.f, nc1 = 0.f, dn0 = 0.f, dn1 = 0.f;
        #pragma unroll
        for (int c = 0; c < 16; ++c) {
            float4 xa = xi4[c];                                    // uniform
            float4 va = vi4[c];                                    // uniform
            float4 xj = xj_r[c];                                   // reg
            float4 vj = *(const float4*)(&vls[l * 68 + c * 4]);    // lds
            float u0 = xa.x - xj.x;
            float u1 = xa.y - xj.y;
            float u2 = xa.z - xj.z;
            float u3 = xa.w - xj.w;
            float e0 = fast_exp2(-(u0 * u0));
            float e1 = fast_exp2(-(u1 * u1));
            float e2 = fast_exp2(-(u2 * u2));
            float e3 = fast_exp2(-(u3 * u3));
            nr0 = fmaf(e0, va.x, nr0);
            nr1 = fmaf(e1, va.y, nr1);
            nr0 = fmaf(e2, va.z, nr0);
            nr1 = fmaf(e3, va.w, nr1);
            nc0 = fmaf(e0, vj.x, nc0);
            nc1 = fmaf(e1, vj.y, nc1);
            nc0 = fmaf(e2, vj.z, nc0);
            nc1 = fmaf(e3, vj.w, nc1);
            dn0 += e0 + e1;
            dn1 += e2 + e3;
        }
        float rd = fast_rcp(dn0 + dn1);
        outb[(size_t)irow * TT + jt * 64 + l] = (nr0 + nr1) * rd;  // coalesced row
        if (isA) cbuf[l * 20 + iloc] = (nc0 + nc1) * rd;           // stash col
    }

    __syncthreads();
    if (isA) {
        // flush col outputs: out[jt*64 + j][i0 .. i0+16), coalesced f4 stores
        int j = tid >> 2, q = tid & 3;
        float4 cv = *(const float4*)(&cbuf[j * 20 + q * 4]);
        *(float4*)(outb + ((size_t)jt * 64 + j) * TT + i0 + q * 4) = cv;
    }
}

extern "C" void kernel_launch(void* const* d_in, const int* in_sizes, int n_in,
                              void* d_out, int out_size, void* d_ws, size_t ws_size,
                              hipStream_t stream) {
    const float* x    = (const float*)d_in[0];
    const float* W    = (const float*)d_in[1];
    const float* bias = (const float*)d_in[2];
    float* out        = (float*)d_out;

    float* xsc = (float*)d_ws;                         // 1 MB
    float* vv  = (float*)((char*)d_ws + (1 << 20));    // 1 MB

    rbf_pre <<<BB * TT / 4, 256, 0, stream>>>(x, W, bias, xsc, vv);
    rbf_pair<<<BB * 144,     256, 0, stream>>>(xsc, vv, out);
}

// Round 6
// 112.059 us; speedup vs baseline: 1.0185x; 1.0185x over previous
//
#include <hip/hip_runtime.h>

#define BB 8
#define TT 512
#define DD 64
#define S_SCALE 1.2011224087864498f   // sqrt(log2(e)); exp(-u^2) = exp2(-(S*u)^2)

typedef float v2f __attribute__((ext_vector_type(2)));

__device__ __forceinline__ float fast_exp2(float v) {
#if __has_builtin(__builtin_amdgcn_exp2f)
    return __builtin_amdgcn_exp2f(v);
#else
    return exp2f(v);
#endif
}
__device__ __forceinline__ float fast_rcp(float v) {
#if __has_builtin(__builtin_amdgcn_rcpf)
    return __builtin_amdgcn_rcpf(v);
#else
    return 1.0f / v;
#endif
}
__device__ __forceinline__ v2f pk_fma(v2f a, v2f b, v2f c) {
#if __has_builtin(__builtin_elementwise_fma)
    return __builtin_elementwise_fma(a, b, c);
#else
    return a * b + c;   // fp-contract fuses; stays packed either way
#endif
}

// ---------------- kernel 1: v = x@W^T + b ; xsc = S*x ----------------
__global__ __launch_bounds__(256) void rbf_pre(
    const float* __restrict__ x, const float* __restrict__ W,
    const float* __restrict__ bias, float* __restrict__ xsc,
    float* __restrict__ vv)
{
    const int t = threadIdx.x;
    const int w = t >> 6, l = t & 63;
    const int row = blockIdx.x * 4 + w;
    const float* xr = x + (size_t)row * DD;
    const float* wr = W + (size_t)l * DD;
    float acc = bias[l];
    #pragma unroll
    for (int d = 0; d < DD; d += 4) {
        float4 xv = *(const float4*)(xr + d);
        float4 wv = *(const float4*)(wr + d);
        acc = fmaf(xv.x, wv.x, acc); acc = fmaf(xv.y, wv.y, acc);
        acc = fmaf(xv.z, wv.z, acc); acc = fmaf(xv.w, wv.w, acc);
    }
    vv [(size_t)row * DD + l] = acc;
    xsc[(size_t)row * DD + l] = xr[l] * S_SCALE;
}

// ---------------- kernel 2: symmetric pairwise tiles ----------------
// Block = 512 thr (8 waves), covers i-strip [32*ti,32*ti+32) x j-tile [64*tj,64*tj+64).
// Launched for ti <= 2*tj+1 (72/batch). Blocks with ti < 2*tj ("A") additionally
// write the mirrored out[j,i] chunk (64 rows x 128 B = full cache lines).
// Lane = j, d serial: num_i, num_j, den accumulate IN-LANE (no reductions).
// xj: 64 VGPRs (one-time LDS transpose). vj: dense LDS. xi/vi: LDS broadcasts.
// Math packed (v_pk_*_f32) except the 4 v_exp_f32 per 4 dims.
__global__ __launch_bounds__(512, 4) void rbf_sym(
    const float* __restrict__ xsc, const float* __restrict__ vv,
    float* __restrict__ out)
{
    const int bid = blockIdx.x;
    const int b = bid / 72;
    int rem = bid - b * 72;
    int tj = 0;
    while (rem >= 2 * tj + 2) { rem -= 2 * tj + 2; ++tj; }  // <=7 scalar iters
    const int ti = rem;
    const bool isA = (ti < 2 * tj);
    const int i0 = ti * 32, j0 = tj * 64;

    const int tid = threadIdx.x;
    const int w = tid >> 6, l = tid & 63;

    __shared__ float jls[64 * 68];     // j-tile staging: xj first, then vj (stride 17 granules)
    __shared__ float xi_s[32 * DD];    // i-strip of xsc
    __shared__ float vi_s[32 * DD];    // i-strip of v
    __shared__ float cbuf[64 * 36];    // mirrored outputs [j][iloc]

    const size_t jbase = ((size_t)b * TT + j0) * DD;
    const size_t ibase = ((size_t)b * TT + i0) * DD;

    // ---- stage xj tile + i-strip (all coalesced f4) ----
    {
        int r0 = tid >> 4, c0 = (tid & 15) * 4;          // granules 0..511
        int g1 = tid + 512;
        int r1 = g1 >> 4, c1 = (g1 & 15) * 4;            // granules 512..1023
        *(float4*)&jls[r0 * 68 + c0] = *(const float4*)(xsc + jbase + (size_t)r0 * DD + c0);
        *(float4*)&jls[r1 * 68 + c1] = *(const float4*)(xsc + jbase + (size_t)r1 * DD + c1);
        *(float4*)&xi_s[r0 * DD + c0] = *(const float4*)(xsc + ibase + (size_t)r0 * DD + c0);
        *(float4*)&vi_s[r0 * DD + c0] = *(const float4*)(vv  + ibase + (size_t)r0 * DD + c0);
    }
    __syncthreads();

    // xj -> registers (conflict-free f4 reads, once per block)
    float4 xj[16];
    #pragma unroll
    for (int c = 0; c < 16; ++c) xj[c] = *(const float4*)&jls[l * 68 + c * 4];
    __syncthreads();

    // ---- overwrite jls with vj tile ----
    {
        int r0 = tid >> 4, c0 = (tid & 15) * 4;
        int g1 = tid + 512;
        int r1 = g1 >> 4, c1 = (g1 & 15) * 4;
        *(float4*)&jls[r0 * 68 + c0] = *(const float4*)(vv + jbase + (size_t)r0 * DD + c0);
        *(float4*)&jls[r1 * 68 + c1] = *(const float4*)(vv + jbase + (size_t)r1 * DD + c1);
    }
    __syncthreads();

    float* outb = out + (size_t)b * TT * TT;

    #pragma unroll 1
    for (int r = 0; r < 4; ++r) {
        const int iloc = w * 4 + r;                       // wave-uniform
        const float4* xi4 = (const float4*)&xi_s[iloc * DD];
        const float4* vi4 = (const float4*)&vi_s[iloc * DD];
        v2f nrA = {0.f, 0.f}, nrB = {0.f, 0.f};
        v2f ncA = {0.f, 0.f}, ncB = {0.f, 0.f};
        v2f dnA = {0.f, 0.f}, dnB = {0.f, 0.f};
        #pragma unroll
        for (int c = 0; c < 16; ++c) {
            float4 xa = xi4[c];                           // LDS broadcast
            float4 va = vi4[c];                           // LDS broadcast
            float4 vj = *(const float4*)&jls[l * 68 + c * 4];  // dense, conflict-free
            float4 xq = xj[c];                            // registers
            v2f u0 = (v2f){xa.x, xa.y} - (v2f){xq.x, xq.y};    // v_pk_add (neg)
            v2f u1 = (v2f){xa.z, xa.w} - (v2f){xq.z, xq.w};
            v2f m0 = u0 * u0;                             // v_pk_mul
            v2f m1 = u1 * u1;
            v2f e0 = {fast_exp2(-m0.x), fast_exp2(-m0.y)};     // neg = input modifier
            v2f e1 = {fast_exp2(-m1.x), fast_exp2(-m1.y)};
            nrA = pk_fma(e0, (v2f){va.x, va.y}, nrA);
            nrB = pk_fma(e1, (v2f){va.z, va.w}, nrB);
            ncA = pk_fma(e0, (v2f){vj.x, vj.y}, ncA);
            ncB = pk_fma(e1, (v2f){vj.z, vj.w}, ncB);
            dnA += e0;                                    // v_pk_add
            dnB += e1;
        }
        float rd   = fast_rcp((dnA.x + dnA.y) + (dnB.x + dnB.y));
        float numr = (nrA.x + nrA.y) + (nrB.x + nrB.y);
        float numc = (ncA.x + ncA.y) + (ncB.x + ncB.y);
        outb[(size_t)(i0 + iloc) * TT + j0 + l] = numr * rd;   // coalesced 256 B
        cbuf[l * 36 + iloc] = numc * rd;                  // stash mirror
    }

    __syncthreads();
    if (isA) {
        // flush mirror: out[j0+j][i0 .. i0+32) -- 64 rows x 128 B full lines
        int j = tid >> 3, q = (tid & 7) * 4;
        float4 cv = *(const float4*)&cbuf[j * 36 + q];
        *(float4*)(outb + (size_t)(j0 + j) * TT + i0 + q) = cv;
    }
}

extern "C" void kernel_launch(void* const* d_in, const int* in_sizes, int n_in,
                              void* d_out, int out_size, void* d_ws, size_t ws_size,
                              hipStream_t stream) {
    const float* x    = (const float*)d_in[0];
    const float* W    = (const float*)d_in[1];
    const float* bias = (const float*)d_in[2];
    float* out        = (float*)d_out;

    float* xsc = (float*)d_ws;                         // 1 MB
    float* vv  = (float*)((char*)d_ws + (1 << 20));    // 1 MB

    rbf_pre<<<BB * TT / 4, 256, 0, stream>>>(x, W, bias, xsc, vv);
    rbf_sym<<<BB * 72, 512, 0, stream>>>(xsc, vv, out);
}

// Round 7
// 89.240 us; speedup vs baseline: 1.2789x; 1.2557x over previous
//
#include <hip/hip_runtime.h>

#define BB 8
#define TT 512
#define DD 64
#define S_SCALE 1.2011224087864498f   // sqrt(log2(e)); exp(-u^2) = exp2(-(S*u)^2)

typedef float v2f __attribute__((ext_vector_type(2)));

__device__ __forceinline__ float fast_exp2(float v) {
#if __has_builtin(__builtin_amdgcn_exp2f)
    return __builtin_amdgcn_exp2f(v);
#else
    return exp2f(v);
#endif
}
__device__ __forceinline__ float fast_rcp(float v) {
#if __has_builtin(__builtin_amdgcn_rcpf)
    return __builtin_amdgcn_rcpf(v);
#else
    return 1.0f / v;
#endif
}
__device__ __forceinline__ v2f pk_fma(v2f a, v2f b, v2f c) {
#if __has_builtin(__builtin_elementwise_fma)
    return __builtin_elementwise_fma(a, b, c);
#else
    return a * b + c;
#endif
}

// ---------------- kernel 1: v = x@W^T + b ; xsc = S*x ----------------
__global__ __launch_bounds__(256) void rbf_pre(
    const float* __restrict__ x, const float* __restrict__ W,
    const float* __restrict__ bias, float* __restrict__ xsc,
    float* __restrict__ vv)
{
    const int t = threadIdx.x;
    const int w = t >> 6, l = t & 63;
    const int row = blockIdx.x * 4 + w;
    const float* xr = x + (size_t)row * DD;
    const float* wr = W + (size_t)l * DD;
    float acc = bias[l];
    #pragma unroll
    for (int d = 0; d < DD; d += 4) {
        float4 xv = *(const float4*)(xr + d);
        float4 wv = *(const float4*)(wr + d);
        acc = fmaf(xv.x, wv.x, acc); acc = fmaf(xv.y, wv.y, acc);
        acc = fmaf(xv.z, wv.z, acc); acc = fmaf(xv.w, wv.w, acc);
    }
    vv [(size_t)row * DD + l] = acc;
    xsc[(size_t)row * DD + l] = xr[l] * S_SCALE;
}

// ---------------- kernel 2: symmetric pairwise tiles ----------------
// Block = 256 thr (4 waves), tile = 32 i x 64 j; launched for ti <= 2*tj+1
// (72/batch, R6-validated coverage). A-blocks (ti < 2*tj) also write mirrored
// out[j,i] via cbuf (128 B line-aligned chunks). Lane = j; wave = 8 i-rows,
// processed in pairs so each dense xj/vj LDS read serves 2 rows. xi/vi are
// wave-uniform LDS broadcasts (cheap). NO register-resident xj array (the
// R5/R6 spill bomb); launch_bounds(256,2) gives 256-VGPR ceiling (LDS caps
// residency at 2 blocks/CU regardless).
__global__ __launch_bounds__(256, 2) void rbf_sym(
    const float* __restrict__ xsc, const float* __restrict__ vv,
    float* __restrict__ out)
{
    const int bid = blockIdx.x;
    const int b = bid / 72;
    int rem = bid - b * 72;
    int tj = 0;
    while (rem >= 2 * tj + 2) { rem -= 2 * tj + 2; ++tj; }
    const int ti = rem;
    const bool isA = (ti < 2 * tj);
    const int i0 = ti * 32, j0 = tj * 64;

    const int tid = threadIdx.x;
    const int w = tid >> 6, l = tid & 63;

    __shared__ float xls[64 * 68];    // xj tile, row stride 68 (16B-aligned, conflict-free)
    __shared__ float vls[64 * 68];    // vj tile
    __shared__ float xi_s[32 * DD];   // i-strip of xsc (broadcast reads)
    __shared__ float vi_s[32 * DD];   // i-strip of v
    __shared__ float cbuf[64 * 36];   // mirror [j][iloc], stride 36 (16B-aligned)

    const size_t jb = ((size_t)b * TT + j0) * DD;
    const size_t ib = ((size_t)b * TT + i0) * DD;

    // ---- stage tiles (all coalesced f4) ----
    {
        const int r = tid >> 4, c4 = (tid & 15) * 4;
        #pragma unroll
        for (int u = 0; u < 4; ++u) {
            int rr = u * 16 + r;
            *(float4*)&xls[rr * 68 + c4] = *(const float4*)(xsc + jb + (size_t)rr * DD + c4);
            *(float4*)&vls[rr * 68 + c4] = *(const float4*)(vv  + jb + (size_t)rr * DD + c4);
        }
        #pragma unroll
        for (int u = 0; u < 2; ++u) {
            int rr = u * 16 + r;
            *(float4*)&xi_s[rr * DD + c4] = *(const float4*)(xsc + ib + (size_t)rr * DD + c4);
            *(float4*)&vi_s[rr * DD + c4] = *(const float4*)(vv  + ib + (size_t)rr * DD + c4);
        }
    }
    __syncthreads();

    float* outb = out + (size_t)b * TT * TT;

    #define ROW_BODY(MIRROR)                                                      \
    _Pragma("unroll 1")                                                           \
    for (int rp = 0; rp < 4; ++rp) {                                              \
        const int ia = w * 8 + rp * 2, ibr = ia + 1;                              \
        const float4* xia = (const float4*)&xi_s[ia * DD];                        \
        const float4* via = (const float4*)&vi_s[ia * DD];                        \
        const float4* xib = (const float4*)&xi_s[ibr * DD];                       \
        const float4* vib = (const float4*)&vi_s[ibr * DD];                       \
        v2f nra0 = {0,0}, nra1 = {0,0}, nca0 = {0,0}, nca1 = {0,0}, dna = {0,0};  \
        v2f nrb0 = {0,0}, nrb1 = {0,0}, ncb0 = {0,0}, ncb1 = {0,0}, dnb = {0,0};  \
        _Pragma("unroll")                                                         \
        for (int c = 0; c < 16; ++c) {                                            \
            float4 xj = *(const float4*)&xls[l * 68 + c * 4];                     \
            float4 vj = *(const float4*)&vls[l * 68 + c * 4];                     \
            float4 xa = xia[c]; float4 va = via[c];                               \
            float4 xb = xib[c]; float4 vb = vib[c];                               \
            v2f ua0 = (v2f){xa.x, xa.y} - (v2f){xj.x, xj.y};                      \
            v2f ua1 = (v2f){xa.z, xa.w} - (v2f){xj.z, xj.w};                      \
            ua0 *= ua0; ua1 *= ua1;                                               \
            v2f ea0 = {fast_exp2(-ua0.x), fast_exp2(-ua0.y)};                     \
            v2f ea1 = {fast_exp2(-ua1.x), fast_exp2(-ua1.y)};                     \
            nra0 = pk_fma(ea0, (v2f){va.x, va.y}, nra0);                          \
            nra1 = pk_fma(ea1, (v2f){va.z, va.w}, nra1);                          \
            if (MIRROR) {                                                         \
                nca0 = pk_fma(ea0, (v2f){vj.x, vj.y}, nca0);                      \
                nca1 = pk_fma(ea1, (v2f){vj.z, vj.w}, nca1);                      \
            }                                                                     \
            dna += ea0 + ea1;                                                     \
            v2f ub0 = (v2f){xb.x, xb.y} - (v2f){xj.x, xj.y};                      \
            v2f ub1 = (v2f){xb.z, xb.w} - (v2f){xj.z, xj.w};                      \
            ub0 *= ub0; ub1 *= ub1;                                               \
            v2f eb0 = {fast_exp2(-ub0.x), fast_exp2(-ub0.y)};                     \
            v2f eb1 = {fast_exp2(-ub1.x), fast_exp2(-ub1.y)};                     \
            nrb0 = pk_fma(eb0, (v2f){vb.x, vb.y}, nrb0);                          \
            nrb1 = pk_fma(eb1, (v2f){vb.z, vb.w}, nrb1);                          \
            if (MIRROR) {                                                         \
                ncb0 = pk_fma(eb0, (v2f){vj.x, vj.y}, ncb0);                      \
                ncb1 = pk_fma(eb1, (v2f){vj.z, vj.w}, ncb1);                      \
            }                                                                     \
            dnb += eb0 + eb1;                                                     \
        }                                                                         \
        float rda = fast_rcp((dna.x + dna.y));                                    \
        float rdb = fast_rcp((dnb.x + dnb.y));                                    \
        outb[(size_t)(i0 + ia)  * TT + j0 + l] =                                  \
            ((nra0.x + nra0.y) + (nra1.x + nra1.y)) * rda;                        \
        outb[(size_t)(i0 + ibr) * TT + j0 + l] =                                  \
            ((nrb0.x + nrb0.y) + (nrb1.x + nrb1.y)) * rdb;                        \
        if (MIRROR) {                                                             \
            cbuf[l * 36 + ia]  = ((nca0.x + nca0.y) + (nca1.x + nca1.y)) * rda;   \
            cbuf[l * 36 + ibr] = ((ncb0.x + ncb0.y) + (ncb1.x + ncb1.y)) * rdb;   \
        }                                                                         \
    }

    if (isA) { ROW_BODY(true) } else { ROW_BODY(false) }
    #undef ROW_BODY

    __syncthreads();
    if (isA) {
        // flush mirror: out[j0+j][i0 .. i0+32) -- 128 B aligned chunks
        #pragma unroll
        for (int u = 0; u < 2; ++u) {
            int g = u * 256 + tid;            // 512 granules = 64 rows x 8 f4
            int j = g >> 3, qf = (g & 7) * 4;
            float4 cv = *(const float4*)&cbuf[j * 36 + qf];
            *(float4*)(outb + (size_t)(j0 + j) * TT + i0 + qf) = cv;
        }
    }
}

extern "C" void kernel_launch(void* const* d_in, const int* in_sizes, int n_in,
                              void* d_out, int out_size, void* d_ws, size_t ws_size,
                              hipStream_t stream) {
    const float* x    = (const float*)d_in[0];
    const float* W    = (const float*)d_in[1];
    const float* bias = (const float*)d_in[2];
    float* out        = (float*)d_out;

    float* xsc = (float*)d_ws;                         // 1 MB
    float* vv  = (float*)((char*)d_ws + (1 << 20));    // 1 MB

    rbf_pre<<<BB * TT / 4, 256, 0, stream>>>(x, W, bias, xsc, vv);
    rbf_sym<<<BB * 72, 256, 0, stream>>>(xsc, vv, out);
}